// Round 21
// baseline (244.390 us; speedup 1.0000x reference)
//
#include <hip/hip_runtime.h>

// ---------------------------------------------------------------------------
// Fused multi-head self-attention, MI355X bf16-MFMA implementation.
// B=4, S=2048, E=1024, H=16, D=64.
// Pipeline: prep (cvt x->bf16 + W^T packs + bias, ONE kernel) |
//           GEMM1 (QKV proj, bias, V written transposed -> VT, 256x128
//           2-phase dbuf) | flash-attn (swapped-QK^T, in-reg softmax,
//           l via ones-MFMA, frag-order LDS K/V dbuf, defer-max) | GEMM2
// ---------------------------------------------------------------------------

typedef __attribute__((ext_vector_type(4)))  float   f32x4;
typedef __attribute__((ext_vector_type(16))) float   f32x16;
typedef __attribute__((ext_vector_type(8)))  __bf16  bf16x8;
typedef __attribute__((ext_vector_type(4)))  __bf16  bf16x4;
typedef __attribute__((ext_vector_type(4)))  unsigned int u32x4;
typedef unsigned int u32;

#if __has_builtin(__builtin_amdgcn_exp2f)
#define EXP2F(x) __builtin_amdgcn_exp2f(x)
#else
#define EXP2F(x) exp2f(x)
#endif

__device__ __forceinline__ f32x4 fzero4() {
    f32x4 z = {0.f, 0.f, 0.f, 0.f};
    return z;
}
__device__ __forceinline__ f32x16 fzero16() {
    f32x16 z;
#pragma unroll
    for (int i = 0; i < 16; i++) z[i] = 0.f;
    return z;
}

__device__ __forceinline__ u32 cvtpk_bf16(float lo, float hi_) {
    u32 r;
    asm("v_cvt_pk_bf16_f32 %0, %1, %2" : "=v"(r) : "v"(lo), "v"(hi_));
    return r;
}

__device__ __forceinline__ void gload_lds16(const void* g, void* l) {
    __builtin_amdgcn_global_load_lds(
        (const __attribute__((address_space(1))) u32*)g,
        (__attribute__((address_space(3))) u32*)l, 16, 0, 0);
}

// ---------------------------------------------------------------------------
// prep: ONE kernel for all preprocessing (replaces 6 launches):
//   blocks [0,8192):     cvt x f32 -> xb bf16 (4 elems/thread, vectorized)
//   blocks [8192,11264):  Wq/Wk/Wv transpose-pack [16][1024][64] -> bf16 W^T
//   blocks [11264,12288): Wo transpose-pack [1024][1024] -> bf16 Wo^T
//   blocks [12288,12300): bias concat {bq,bk,bv} -> bqkv
// Per-block logic identical to the previous separate kernels.
// ---------------------------------------------------------------------------
__global__ __launch_bounds__(256) void prep(
    const float* __restrict__ x,  __bf16* __restrict__ xb,
    const float* __restrict__ Wq, const float* __restrict__ Wk,
    const float* __restrict__ Wv, const float* __restrict__ Wo,
    __bf16* __restrict__ Wqkv, __bf16* __restrict__ Wot,
    const float* __restrict__ bq, const float* __restrict__ bk,
    const float* __restrict__ bv, float* __restrict__ bqkv) {
    __shared__ float t[32][33];
    const int tid = threadIdx.x;
    int bid = blockIdx.x;

    if (bid < 8192) {                       // ---- cvt x -> bf16 ----
        long i = ((long)bid * 256 + tid) * 4;
        float4 v = *(const float4*)(x + i);
        bf16x4 o = { (__bf16)v.x, (__bf16)v.y, (__bf16)v.z, (__bf16)v.w };
        *(bf16x4*)(xb + i) = o;
        return;
    }
    bid -= 8192;
    if (bid < 4096) {                       // ---- transpose packs ----
        const float* src;
        __bf16* dst;
        int C, r0, c0;
        if (bid < 3072) {                   // Wq/Wk/Wv: per-head [1024][64]
            const int g = bid >> 10, rem = bid & 1023;
            const float* W = (g == 0) ? Wq : (g == 1) ? Wk : Wv;
            const int z = rem >> 6, bx = rem & 31, by = (rem >> 5) & 1;
            C = 64;
            src = W + (size_t)z * 1024 * 64;
            dst = Wqkv + (size_t)g * 1024 * 1024 + (size_t)z * 1024 * 64;
            r0 = bx * 32; c0 = by * 32;
        } else {                            // Wo: [1024][1024]
            const int rem = bid - 3072;
            const int bx = rem & 31, by = rem >> 5;
            C = 1024;
            src = Wo; dst = Wot;
            r0 = bx * 32; c0 = by * 32;
        }
        const int xx = tid & 31, yy = tid >> 5;
#pragma unroll
        for (int i = 0; i < 4; i++)
            t[yy + i * 8][xx] = src[(size_t)(r0 + yy + i * 8) * C + c0 + xx];
        __syncthreads();
#pragma unroll
        for (int i = 0; i < 4; i++)
            dst[(size_t)(c0 + yy + i * 8) * 1024 + r0 + xx] =
                (__bf16)t[xx][yy + i * 8];
        return;
    }
    const int n = (bid - 4096) * 256 + tid; // ---- bias concat ----
    if (n < 3072) {
        const int tt = n >> 10, r = n & 1023;
        const float* s = (tt == 0) ? bq : (tt == 1) ? bk : bv;
        bqkv[n] = s[r];
    }
}

// ---------------------------------------------------------------------------
// GEMM, 256x128 tile (BM=256, BN=128), BK=32, 512 threads = 8 waves (4Mx2N),
// per-wave output 64x64, T3 2-phase LDS double-buffer (r17/r20, unchanged).
// ---------------------------------------------------------------------------
#define GEMM_STAGE(BUF, KOFF)                                                  \
  {                                                                            \
    gload_lds16(A + arow0 * K + (KOFF) + kcol,                                 \
                (char*)As + (BUF) * 16384 + wid * 1024);                       \
    gload_lds16(A + arow1 * K + (KOFF) + kcol,                                 \
                (char*)As + (BUF) * 16384 + 8192 + wid * 1024);                \
    gload_lds16(Bt + brow * K + (KOFF) + kcol,                                 \
                (char*)Bs + (BUF) * 8192 + wid * 1024);                        \
  }

#define GEMM_COMPUTE(BUF)                                                      \
  {                                                                            \
    bf16x8 a[4], b[4];                                                         \
    _Pragma("unroll")                                                          \
    for (int mi = 0; mi < 4; mi++)                                             \
      a[mi] = *(const bf16x8*)&As[(BUF) * 8192 +                               \
                                  (mr * 64 + mi * 16 + l15) * 32 + l4 * 8];    \
    _Pragma("unroll")                                                          \
    for (int ni = 0; ni < 4; ni++)                                             \
      b[ni] = *(const bf16x8*)&Bs[(BUF) * 4096 +                               \
                                  (nc * 64 + ni * 16 + l15) * 32 + l4 * 8];    \
    _Pragma("unroll")                                                          \
    for (int mi = 0; mi < 4; mi++)                                             \
      _Pragma("unroll")                                                        \
      for (int ni = 0; ni < 4; ni++)                                           \
        acc[mi][ni] = __builtin_amdgcn_mfma_f32_16x16x32_bf16(                 \
            a[mi], b[ni], acc[mi][ni], 0, 0, 0);                               \
  }

#define GEMM_PREAMBLE                                                          \
    const int tid  = threadIdx.x;                                              \
    const int lane = tid & 63, wid = tid >> 6;                                 \
    const int mr = wid >> 1, nc = wid & 1;                                     \
    const int l15 = lane & 15, l4 = lane >> 4;                                 \
    const int bn = blockIdx.x, bm = blockIdx.y;                                \
    const long arow0 = (long)bm * 256 + (tid >> 2);                            \
    const long arow1 = arow0 + 128;                                            \
    const long brow  = (long)bn * 128 + (tid >> 2);                            \
    const int  kcol  = (tid & 3) * 8;                                          \
    f32x4 acc[4][4];                                                           \
    _Pragma("unroll")                                                          \
    for (int i = 0; i < 4; i++)                                                \
      _Pragma("unroll")                                                        \
      for (int j = 0; j < 4; j++) acc[i][j] = fzero4();                        \
    GEMM_STAGE(0, 0)                                                           \
    __syncthreads();                                                           \
    int cur = 0;                                                               \
    for (int k0 = 0; k0 < K; k0 += 32, cur ^= 1) {                             \
        if (k0 + 32 < K) GEMM_STAGE(cur ^ 1, k0 + 32)                          \
        GEMM_COMPUTE(cur)                                                      \
        __syncthreads();                                                       \
    }

template <bool F32OUT>
__global__ __launch_bounds__(512) void gemm_bt(
    const __bf16* __restrict__ A, const __bf16* __restrict__ Bt,
    const float* __restrict__ bias, void* __restrict__ Cout,
    int M, int N, int K, int ldc) {
    __shared__ __bf16 As[2 * 256 * 32];
    __shared__ __bf16 Bs[2 * 128 * 32];
    GEMM_PREAMBLE

#pragma unroll
    for (int mi = 0; mi < 4; mi++)
#pragma unroll
        for (int ni = 0; ni < 4; ni++) {
            const int row = bm * 256 + mr * 64 + mi * 16 + l4 * 4;
            const int col = bn * 128 + nc * 64 + ni * 16 + l15;
            const float bv = bias ? bias[col] : 0.f;
#pragma unroll
            for (int r = 0; r < 4; r++) {
                float v = acc[mi][ni][r] + bv;
                if (F32OUT)
                    ((float*)Cout)[(long)(row + r) * ldc + col] = v;
                else
                    ((__bf16*)Cout)[(long)(row + r) * ldc + col] = (__bf16)v;
            }
        }
}

__global__ __launch_bounds__(512) void gemm_qkv(
    const __bf16* __restrict__ A, const __bf16* __restrict__ Bt,
    const float* __restrict__ bias, __bf16* __restrict__ QKV,
    __bf16* __restrict__ VT, int K) {
    __shared__ __bf16 As[2 * 256 * 32];
    __shared__ __bf16 Bs[2 * 128 * 32];
    GEMM_PREAMBLE

    if (bn < 16) {
#pragma unroll
        for (int mi = 0; mi < 4; mi++)
#pragma unroll
            for (int ni = 0; ni < 4; ni++) {
                const int row = bm * 256 + mr * 64 + mi * 16 + l4 * 4;
                const int col = bn * 128 + nc * 64 + ni * 16 + l15;
                const float bv = bias[col];
#pragma unroll
                for (int r = 0; r < 4; r++)
                    QKV[(long)(row + r) * 3072 + col] =
                        (__bf16)(acc[mi][ni][r] + bv);
            }
    } else {
#pragma unroll
        for (int mi = 0; mi < 4; mi++)
#pragma unroll
            for (int ni = 0; ni < 4; ni++) {
                const int row = bm * 256 + mr * 64 + mi * 16 + l4 * 4;
                const int col = bn * 128 + nc * 64 + ni * 16 + l15;
                const float bv = bias[col];
                const int vcol = col - 2048;
                const int h = vcol >> 6, dcol = vcol & 63;
                const int bb = row >> 11, s = row & 2047;
                bf16x4 o;
#pragma unroll
                for (int r = 0; r < 4; r++)
                    o[r] = (__bf16)(acc[mi][ni][r] + bv);
                *(bf16x4*)&VT[((size_t)(bb * 16 + h) * 64 + dcol) * 2048 + s] = o;
            }
    }
}

// ---------------------------------------------------------------------------
// Flash attention fwd, v14 = r17 single-q-set structure + l via ones-MFMA:
// the 31-op VALU sum-tree + cross-half shfl per tile is replaced by
// l_acc = mfma(ones, P^T, l_acc) per kkt (4 extra MFMAs on the 29%-busy
// matrix pipe; VALU pipe is at 52%). Every row of l_acc receives the same
// Sum_k P[k][q], and defer-max rescale scales only element 0 -- the only
// element ever read -- which therefore tracks the exact online l.
// Swapped-QK^T, frag-order LDS K/V dbuf, defer-max, (256,4), XCD swizzle.
// Block = (b, h, 128-row Q tile); 4 waves x 32 q-rows. KV tile = 64.
// ---------------------------------------------------------------------------
__global__ __launch_bounds__(256, 4) void attn_fwd(
    const __bf16* __restrict__ QKV, const __bf16* __restrict__ VT,
    __bf16* __restrict__ Z) {
    const int S = 2048, LDQ = 3072;
    const int dd = blockIdx.x;
    const int blk = (dd & 7) * 128 + (dd >> 3);
    const int qt = blk & 15, bh = blk >> 4, b = bh >> 4, h = bh & 15;
    const int tid = threadIdx.x, wid = tid >> 6, lane = tid & 63;
    const int l31 = lane & 31, hi = lane >> 5;

    __shared__ __bf16 smem[16384];   // 32 KB

    const __bf16* Qb = QKV + (size_t)b * S * LDQ + h * 64;
    const __bf16* Kb = Qb + 1024;
    const __bf16* Vb = VT + (size_t)bh * 64 * S;
    const int qrow = qt * 128 + wid * 32;

    bf16x8 qf[4];
#pragma unroll
    for (int kk = 0; kk < 4; kk++)
        qf[kk] = *(const bf16x8*)(Qb + (size_t)(qrow + l31) * LDQ + kk * 16 + hi * 8);

    const int f0 = wid * 2, f1 = wid * 2 + 1;
    const int kr0 = (f0 >> 2) * 32 + l31, kc0 = (f0 & 3) * 16 + hi * 8;
    const int kr1 = (f1 >> 2) * 32 + l31, kc1 = (f1 & 3) * 16 + hi * 8;
    const int vr0 = kr0, vs0 = kc0;
    const int vr1 = kr1, vs1 = kc1;
    const int ldst = lane * 16;

    f32x16 o0 = fzero16(), o1 = fzero16(), l_acc = fzero16();
    float m_r = -1e30f;
    const float csc = 0.18033688011f;   // log2(e) / sqrt(64)
    const __bf16 onebf = (__bf16)1.0f;
    const bf16x8 ones8 = {onebf, onebf, onebf, onebf, onebf, onebf, onebf, onebf};

    gload_lds16(Kb + (size_t)kr0 * LDQ + kc0, (char*)smem + f0 * 1024 + ldst);
    gload_lds16(Kb + (size_t)kr1 * LDQ + kc1, (char*)smem + f1 * 1024 + ldst);
    gload_lds16(Vb + (size_t)vr0 * S + vs0,   (char*)smem + 16384 + f0 * 1024 + ldst);
    gload_lds16(Vb + (size_t)vr1 * S + vs1,   (char*)smem + 16384 + f1 * 1024 + ldst);
    asm volatile("s_waitcnt vmcnt(0)" ::: "memory");
    __syncthreads();

    int cur = 0;
    for (int t0 = 0; t0 < S; t0 += 64, cur ^= 1) {
        if (t0 + 64 < S) {
            char* kl = (char*)smem + (cur ^ 1) * 8192;
            char* vl = (char*)smem + 16384 + (cur ^ 1) * 8192;
            gload_lds16(Kb + (size_t)(t0 + 64 + kr0) * LDQ + kc0, kl + f0 * 1024 + ldst);
            gload_lds16(Kb + (size_t)(t0 + 64 + kr1) * LDQ + kc1, kl + f1 * 1024 + ldst);
            gload_lds16(Vb + (size_t)vr0 * S + t0 + 64 + vs0,     vl + f0 * 1024 + ldst);
            gload_lds16(Vb + (size_t)vr1 * S + t0 + 64 + vs1,     vl + f1 * 1024 + ldst);
        }
        const char* kbase = (const char*)smem + cur * 8192;
        const char* vbase = (const char*)smem + 16384 + cur * 8192;

        // ---- K frags from LDS (frag-order) + QK^T ----
        bf16x8 kf[8];
#pragma unroll
        for (int f = 0; f < 8; f++)
            kf[f] = *(const bf16x8*)(kbase + f * 1024 + ldst);
        f32x16 s0 = fzero16(), s1 = fzero16();
        __builtin_amdgcn_s_setprio(1);
#pragma unroll
        for (int kk = 0; kk < 4; kk++) {
            s0 = __builtin_amdgcn_mfma_f32_32x32x16_bf16(kf[kk],     qf[kk], s0, 0, 0, 0);
            s1 = __builtin_amdgcn_mfma_f32_32x32x16_bf16(kf[4 + kk], qf[kk], s1, 0, 0, 0);
        }
        __builtin_amdgcn_s_setprio(0);

        // ---- online softmax: tree max + defer-max rescale ----
        float mm[16];
#pragma unroll
        for (int i = 0; i < 16; i++) mm[i] = fmaxf(s0[i], s1[i]);
#pragma unroll
        for (int st = 8; st >= 1; st >>= 1)
#pragma unroll
            for (int i = 0; i < st; i++) mm[i] = fmaxf(mm[i], mm[i + st]);
        const float pm = fmaxf(mm[0], __shfl_xor(mm[0], 32));
        if (!__all(pm - m_r <= 64.f)) {          // 64 raw units = e^8 bound
            const float mnew = fmaxf(m_r, pm);
            const float alpha = EXP2F((m_r - mnew) * csc);
            m_r = mnew;
            l_acc[0] *= alpha;                   // only elem 0 is ever read
#pragma unroll
            for (int i = 0; i < 16; i++) { o0[i] *= alpha; o1[i] *= alpha; }
        }
        const float mc = m_r * csc;
#pragma unroll
        for (int i = 0; i < 16; i++) {
            s0[i] = EXP2F(s0[i] * csc - mc);
            s1[i] = EXP2F(s1[i] * csc - mc);
        }

        // ---- P -> bf16 B-frags in-register; PV + l on the MFMA pipe ----
        __builtin_amdgcn_s_setprio(1);
#pragma unroll
        for (int kkt = 0; kkt < 4; kkt++) {
            const int r0 = (kkt & 1) * 8;
            u32 w0, w1, w2, w3;
            if (kkt < 2) {
                w0 = cvtpk_bf16(s0[r0],     s0[r0 + 1]);
                w1 = cvtpk_bf16(s0[r0 + 2], s0[r0 + 3]);
                w2 = cvtpk_bf16(s0[r0 + 4], s0[r0 + 5]);
                w3 = cvtpk_bf16(s0[r0 + 6], s0[r0 + 7]);
            } else {
                w0 = cvtpk_bf16(s1[r0],     s1[r0 + 1]);
                w1 = cvtpk_bf16(s1[r0 + 2], s1[r0 + 3]);
                w2 = cvtpk_bf16(s1[r0 + 4], s1[r0 + 5]);
                w3 = cvtpk_bf16(s1[r0 + 6], s1[r0 + 7]);
            }
            asm("v_permlane32_swap_b32 %0, %1" : "+v"(w0), "+v"(w2));
            asm("v_permlane32_swap_b32 %0, %1" : "+v"(w1), "+v"(w3));
            u32x4 pw = {w0, w1, w2, w3};
            bf16x8 pf = __builtin_bit_cast(bf16x8, pw);
            bf16x8 vf0 = *(const bf16x8*)(vbase + kkt * 1024 + ldst);
            bf16x8 vf1 = *(const bf16x8*)(vbase + (4 + kkt) * 1024 + ldst);
            o0 = __builtin_amdgcn_mfma_f32_32x32x16_bf16(vf0, pf, o0, 0, 0, 0);
            o1 = __builtin_amdgcn_mfma_f32_32x32x16_bf16(vf1, pf, o1, 0, 0, 0);
            l_acc = __builtin_amdgcn_mfma_f32_32x32x16_bf16(ones8, pf, l_acc, 0, 0, 0);
        }
        __builtin_amdgcn_s_setprio(0);

        asm volatile("s_waitcnt vmcnt(0)" ::: "memory");
        __syncthreads();
    }

    // ---- epilogue: normalize, transpose via LDS (overlays smem), store ----
    const float inv = 1.0f / l_acc[0];
    __bf16 (*Tl)[72] = (__bf16 (*)[72])smem;
    const int trow = wid * 32 + l31;
#pragma unroll
    for (int g = 0; g < 4; g++) {
        bf16x4 t4a, t4b;
#pragma unroll
        for (int j = 0; j < 4; j++) {
            t4a[j] = (__bf16)(o0[4 * g + j] * inv);
            t4b[j] = (__bf16)(o1[4 * g + j] * inv);
        }
        *(bf16x4*)&Tl[trow][g * 8 + hi * 4]      = t4a;   // d = 8g+4hi+j
        *(bf16x4*)&Tl[trow][32 + g * 8 + hi * 4] = t4b;   // d = 32+8g+4hi+j
    }
    asm volatile("s_waitcnt lgkmcnt(0)" ::: "memory");
    __builtin_amdgcn_sched_barrier(0);

    const int rr = wid * 32 + (lane >> 1);
    const int ch = (lane & 1) * 32;
#pragma unroll
    for (int i = 0; i < 4; i++) {
        bf16x8 z = *(const bf16x8*)&Tl[rr][ch + i * 8];
        *(bf16x8*)&Z[((size_t)b * S + qt * 128 + rr) * 1024 + h * 64 + ch + i * 8] = z;
    }
}

// ---------------------------------------------------------------------------
// Launcher (4 kernels total)
// ---------------------------------------------------------------------------
extern "C" void kernel_launch(void* const* d_in, const int* in_sizes, int n_in,
                              void* d_out, int out_size, void* d_ws, size_t ws_size,
                              hipStream_t stream) {
    const float* x  = (const float*)d_in[0];
    const float* Wq = (const float*)d_in[1];
    const float* Wk = (const float*)d_in[2];
    const float* Wv = (const float*)d_in[3];
    const float* bq = (const float*)d_in[4];
    const float* bk = (const float*)d_in[5];
    const float* bv = (const float*)d_in[6];
    const float* Wo = (const float*)d_in[7];
    const float* bo = (const float*)d_in[8];
    float* out = (float*)d_out;

    // workspace carve-up (~109 MB)
    char* p = (char*)d_ws;
    __bf16* xb   = (__bf16*)p; p += 8192L * 1024 * 2;
    __bf16* Wqkv = (__bf16*)p; p += 3072L * 1024 * 2;
    float*  bqkv = (float*)p;  p += 3072L * 4;
    __bf16* QKV  = (__bf16*)p; p += 8192L * 3072 * 2;
    __bf16* VTb  = (__bf16*)p; p += 64L * 64 * 2048 * 2;
    __bf16* Zb   = (__bf16*)p; p += 8192L * 1024 * 2;
    __bf16* Wot  = (__bf16*)p; p += 1024L * 1024 * 2;

    // all preprocessing in one launch: 8192 cvt + 4096 packs + 12 bias blocks
    prep<<<12300, 256, 0, stream>>>(x, xb, Wq, Wk, Wv, Wo, Wqkv, Wot,
                                    bq, bk, bv, bqkv);

    // QKV projection: [8192,1024] x [1024,3072] + bias; Q,K -> QKV row-major,
    // V -> VT transposed. 256x128 tile, 512 threads.
    gemm_qkv<<<dim3(24, 32), 512, 0, stream>>>(xb, Wqkv, bqkv, QKV, VTb, 1024);
    attn_fwd<<<1024, 256, 0, stream>>>(QKV, VTb, Zb);
    // out projection: [8192,1024] x [1024,1024] + bo -> f32 out
    gemm_bt<true><<<dim3(8, 32), 512, 0, stream>>>(Zb, Wot, bo, out,
                                                   8192, 1024, 1024, 1024);
}

// Round 22
// 211.725 us; speedup vs baseline: 1.1543x; 1.1543x over previous
//
#include <hip/hip_runtime.h>

// ---------------------------------------------------------------------------
// Fused multi-head self-attention, MI355X bf16-MFMA implementation.
// B=4, S=2048, E=1024, H=16, D=64.
// Pipeline: prep (cvt x->bf16 + W^T packs + bias, ONE kernel) |
//           GEMM1 (QKV proj, bias, V written transposed -> VT, 256x128
//           2-phase dbuf) | flash-attn (r18: swapped-QK^T, 2 q-sets/wave,
//           in-reg softmax, frag-order LDS K/V dbuf, defer-max) | GEMM2
// ---------------------------------------------------------------------------

typedef __attribute__((ext_vector_type(4)))  float   f32x4;
typedef __attribute__((ext_vector_type(16))) float   f32x16;
typedef __attribute__((ext_vector_type(8)))  __bf16  bf16x8;
typedef __attribute__((ext_vector_type(4)))  __bf16  bf16x4;
typedef __attribute__((ext_vector_type(4)))  unsigned int u32x4;
typedef unsigned int u32;

#if __has_builtin(__builtin_amdgcn_exp2f)
#define EXP2F(x) __builtin_amdgcn_exp2f(x)
#else
#define EXP2F(x) exp2f(x)
#endif

__device__ __forceinline__ f32x4 fzero4() {
    f32x4 z = {0.f, 0.f, 0.f, 0.f};
    return z;
}
__device__ __forceinline__ f32x16 fzero16() {
    f32x16 z;
#pragma unroll
    for (int i = 0; i < 16; i++) z[i] = 0.f;
    return z;
}

__device__ __forceinline__ u32 cvtpk_bf16(float lo, float hi_) {
    u32 r;
    asm("v_cvt_pk_bf16_f32 %0, %1, %2" : "=v"(r) : "v"(lo), "v"(hi_));
    return r;
}

__device__ __forceinline__ void gload_lds16(const void* g, void* l) {
    __builtin_amdgcn_global_load_lds(
        (const __attribute__((address_space(1))) u32*)g,
        (__attribute__((address_space(3))) u32*)l, 16, 0, 0);
}

// ---------------------------------------------------------------------------
// prep: ONE kernel for all preprocessing (r21-proven, ~14us saved):
//   blocks [0,8192):      cvt x f32 -> xb bf16 (4 elems/thread, vectorized)
//   blocks [8192,11264):  Wq/Wk/Wv transpose-pack [16][1024][64] -> bf16 W^T
//   blocks [11264,12288): Wo transpose-pack [1024][1024] -> bf16 Wo^T
//   blocks [12288,12300): bias concat {bq,bk,bv} -> bqkv
// ---------------------------------------------------------------------------
__global__ __launch_bounds__(256) void prep(
    const float* __restrict__ x,  __bf16* __restrict__ xb,
    const float* __restrict__ Wq, const float* __restrict__ Wk,
    const float* __restrict__ Wv, const float* __restrict__ Wo,
    __bf16* __restrict__ Wqkv, __bf16* __restrict__ Wot,
    const float* __restrict__ bq, const float* __restrict__ bk,
    const float* __restrict__ bv, float* __restrict__ bqkv) {
    __shared__ float t[32][33];
    const int tid = threadIdx.x;
    int bid = blockIdx.x;

    if (bid < 8192) {                       // ---- cvt x -> bf16 ----
        long i = ((long)bid * 256 + tid) * 4;
        float4 v = *(const float4*)(x + i);
        bf16x4 o = { (__bf16)v.x, (__bf16)v.y, (__bf16)v.z, (__bf16)v.w };
        *(bf16x4*)(xb + i) = o;
        return;
    }
    bid -= 8192;
    if (bid < 4096) {                       // ---- transpose packs ----
        const float* src;
        __bf16* dst;
        int C, r0, c0;
        if (bid < 3072) {                   // Wq/Wk/Wv: per-head [1024][64]
            const int g = bid >> 10, rem = bid & 1023;
            const float* W = (g == 0) ? Wq : (g == 1) ? Wk : Wv;
            const int z = rem >> 6, bx = rem & 31, by = (rem >> 5) & 1;
            C = 64;
            src = W + (size_t)z * 1024 * 64;
            dst = Wqkv + (size_t)g * 1024 * 1024 + (size_t)z * 1024 * 64;
            r0 = bx * 32; c0 = by * 32;
        } else {                            // Wo: [1024][1024]
            const int rem = bid - 3072;
            const int bx = rem & 31, by = rem >> 5;
            C = 1024;
            src = Wo; dst = Wot;
            r0 = bx * 32; c0 = by * 32;
        }
        const int xx = tid & 31, yy = tid >> 5;
#pragma unroll
        for (int i = 0; i < 4; i++)
            t[yy + i * 8][xx] = src[(size_t)(r0 + yy + i * 8) * C + c0 + xx];
        __syncthreads();
#pragma unroll
        for (int i = 0; i < 4; i++)
            dst[(size_t)(c0 + yy + i * 8) * 1024 + r0 + xx] =
                (__bf16)t[xx][yy + i * 8];
        return;
    }
    const int n = (bid - 4096) * 256 + tid; // ---- bias concat ----
    if (n < 3072) {
        const int tt = n >> 10, r = n & 1023;
        const float* s = (tt == 0) ? bq : (tt == 1) ? bk : bv;
        bqkv[n] = s[r];
    }
}

// ---------------------------------------------------------------------------
// GEMM, 256x128 tile (BM=256, BN=128), BK=32, 512 threads = 8 waves (4Mx2N),
// per-wave output 64x64, T3 2-phase LDS double-buffer (r17/r20, unchanged).
// ---------------------------------------------------------------------------
#define GEMM_STAGE(BUF, KOFF)                                                  \
  {                                                                            \
    gload_lds16(A + arow0 * K + (KOFF) + kcol,                                 \
                (char*)As + (BUF) * 16384 + wid * 1024);                       \
    gload_lds16(A + arow1 * K + (KOFF) + kcol,                                 \
                (char*)As + (BUF) * 16384 + 8192 + wid * 1024);                \
    gload_lds16(Bt + brow * K + (KOFF) + kcol,                                 \
                (char*)Bs + (BUF) * 8192 + wid * 1024);                        \
  }

#define GEMM_COMPUTE(BUF)                                                      \
  {                                                                            \
    bf16x8 a[4], b[4];                                                         \
    _Pragma("unroll")                                                          \
    for (int mi = 0; mi < 4; mi++)                                             \
      a[mi] = *(const bf16x8*)&As[(BUF) * 8192 +                               \
                                  (mr * 64 + mi * 16 + l15) * 32 + l4 * 8];    \
    _Pragma("unroll")                                                          \
    for (int ni = 0; ni < 4; ni++)                                             \
      b[ni] = *(const bf16x8*)&Bs[(BUF) * 4096 +                               \
                                  (nc * 64 + ni * 16 + l15) * 32 + l4 * 8];    \
    _Pragma("unroll")                                                          \
    for (int mi = 0; mi < 4; mi++)                                             \
      _Pragma("unroll")                                                        \
      for (int ni = 0; ni < 4; ni++)                                           \
        acc[mi][ni] = __builtin_amdgcn_mfma_f32_16x16x32_bf16(                 \
            a[mi], b[ni], acc[mi][ni], 0, 0, 0);                               \
  }

#define GEMM_PREAMBLE                                                          \
    const int tid  = threadIdx.x;                                              \
    const int lane = tid & 63, wid = tid >> 6;                                 \
    const int mr = wid >> 1, nc = wid & 1;                                     \
    const int l15 = lane & 15, l4 = lane >> 4;                                 \
    const int bn = blockIdx.x, bm = blockIdx.y;                                \
    const long arow0 = (long)bm * 256 + (tid >> 2);                            \
    const long arow1 = arow0 + 128;                                            \
    const long brow  = (long)bn * 128 + (tid >> 2);                            \
    const int  kcol  = (tid & 3) * 8;                                          \
    f32x4 acc[4][4];                                                           \
    _Pragma("unroll")                                                          \
    for (int i = 0; i < 4; i++)                                                \
      _Pragma("unroll")                                                        \
      for (int j = 0; j < 4; j++) acc[i][j] = fzero4();                        \
    GEMM_STAGE(0, 0)                                                           \
    __syncthreads();                                                           \
    int cur = 0;                                                               \
    for (int k0 = 0; k0 < K; k0 += 32, cur ^= 1) {                             \
        if (k0 + 32 < K) GEMM_STAGE(cur ^ 1, k0 + 32)                          \
        GEMM_COMPUTE(cur)                                                      \
        __syncthreads();                                                       \
    }

template <bool F32OUT>
__global__ __launch_bounds__(512) void gemm_bt(
    const __bf16* __restrict__ A, const __bf16* __restrict__ Bt,
    const float* __restrict__ bias, void* __restrict__ Cout,
    int M, int N, int K, int ldc) {
    __shared__ __bf16 As[2 * 256 * 32];
    __shared__ __bf16 Bs[2 * 128 * 32];
    GEMM_PREAMBLE

#pragma unroll
    for (int mi = 0; mi < 4; mi++)
#pragma unroll
        for (int ni = 0; ni < 4; ni++) {
            const int row = bm * 256 + mr * 64 + mi * 16 + l4 * 4;
            const int col = bn * 128 + nc * 64 + ni * 16 + l15;
            const float bv = bias ? bias[col] : 0.f;
#pragma unroll
            for (int r = 0; r < 4; r++) {
                float v = acc[mi][ni][r] + bv;
                if (F32OUT)
                    ((float*)Cout)[(long)(row + r) * ldc + col] = v;
                else
                    ((__bf16*)Cout)[(long)(row + r) * ldc + col] = (__bf16)v;
            }
        }
}

__global__ __launch_bounds__(512) void gemm_qkv(
    const __bf16* __restrict__ A, const __bf16* __restrict__ Bt,
    const float* __restrict__ bias, __bf16* __restrict__ QKV,
    __bf16* __restrict__ VT, int K) {
    __shared__ __bf16 As[2 * 256 * 32];
    __shared__ __bf16 Bs[2 * 128 * 32];
    GEMM_PREAMBLE

    if (bn < 16) {
#pragma unroll
        for (int mi = 0; mi < 4; mi++)
#pragma unroll
            for (int ni = 0; ni < 4; ni++) {
                const int row = bm * 256 + mr * 64 + mi * 16 + l4 * 4;
                const int col = bn * 128 + nc * 64 + ni * 16 + l15;
                const float bv = bias[col];
#pragma unroll
                for (int r = 0; r < 4; r++)
                    QKV[(long)(row + r) * 3072 + col] =
                        (__bf16)(acc[mi][ni][r] + bv);
            }
    } else {
#pragma unroll
        for (int mi = 0; mi < 4; mi++)
#pragma unroll
            for (int ni = 0; ni < 4; ni++) {
                const int row = bm * 256 + mr * 64 + mi * 16 + l4 * 4;
                const int col = bn * 128 + nc * 64 + ni * 16 + l15;
                const float bv = bias[col];
                const int vcol = col - 2048;
                const int h = vcol >> 6, dcol = vcol & 63;
                const int bb = row >> 11, s = row & 2047;
                bf16x4 o;
#pragma unroll
                for (int r = 0; r < 4; r++)
                    o[r] = (__bf16)(acc[mi][ni][r] + bv);
                *(bf16x4*)&VT[((size_t)(bb * 16 + h) * 64 + dcol) * 2048 + s] = o;
            }
    }
}

// ---------------------------------------------------------------------------
// Flash attention fwd (r18/r20, 103us proven): swapped-QK^T, 2 q-sets/wave,
// in-reg softmax (VALU tree), frag-order LDS K/V dbuf, defer-max, XCD swizzle.
// Block = (b, h, 256-row Q tile); 4 waves x 2x32 q-rows. KV tile = 64.
//   S^T = mfma(A=K, B=Q):   lane q-col = lane&31 -> ONE q row per lane.
//   O^T = mfma(A=V^T, B=P^T): same lane->q mapping, scalar m/l/alpha.
// ---------------------------------------------------------------------------
#define ATTN_SM_PV(S0, S1, M_R, L_R, O0, O1)                                   \
  {                                                                            \
    float mm[16];                                                              \
    _Pragma("unroll")                                                          \
    for (int i = 0; i < 16; i++) mm[i] = fmaxf(S0[i], S1[i]);                  \
    _Pragma("unroll")                                                          \
    for (int st = 8; st >= 1; st >>= 1)                                        \
      _Pragma("unroll")                                                        \
      for (int i = 0; i < st; i++) mm[i] = fmaxf(mm[i], mm[i + st]);           \
    const float pm = fmaxf(mm[0], __shfl_xor(mm[0], 32));                      \
    if (!__all(pm - M_R <= 64.f)) {        /* 64 raw units = e^8 bound */      \
      const float mnew = fmaxf(M_R, pm);                                       \
      const float alpha = EXP2F((M_R - mnew) * csc);                           \
      M_R = mnew;                                                              \
      L_R *= alpha;                                                            \
      _Pragma("unroll")                                                        \
      for (int i = 0; i < 16; i++) { O0[i] *= alpha; O1[i] *= alpha; }         \
    }                                                                          \
    const float mc = M_R * csc;                                                \
    float ss[16];                                                              \
    _Pragma("unroll")                                                          \
    for (int i = 0; i < 16; i++) {                                             \
      float p0 = EXP2F(S0[i] * csc - mc); S0[i] = p0;                          \
      float p1 = EXP2F(S1[i] * csc - mc); S1[i] = p1;                          \
      ss[i] = p0 + p1;                                                         \
    }                                                                          \
    _Pragma("unroll")                                                          \
    for (int st = 8; st >= 1; st >>= 1)                                        \
      _Pragma("unroll")                                                        \
      for (int i = 0; i < st; i++) ss[i] += ss[i + st];                        \
    L_R += ss[0] + __shfl_xor(ss[0], 32);                                      \
    __builtin_amdgcn_s_setprio(1);                                             \
    _Pragma("unroll")                                                          \
    for (int kkt = 0; kkt < 4; kkt++) {                                        \
      const int r0 = (kkt & 1) * 8;                                            \
      u32 w0, w1, w2, w3;                                                      \
      if (kkt < 2) {                                                           \
        w0 = cvtpk_bf16(S0[r0],     S0[r0 + 1]);                               \
        w1 = cvtpk_bf16(S0[r0 + 2], S0[r0 + 3]);                               \
        w2 = cvtpk_bf16(S0[r0 + 4], S0[r0 + 5]);                               \
        w3 = cvtpk_bf16(S0[r0 + 6], S0[r0 + 7]);                               \
      } else {                                                                 \
        w0 = cvtpk_bf16(S1[r0],     S1[r0 + 1]);                               \
        w1 = cvtpk_bf16(S1[r0 + 2], S1[r0 + 3]);                               \
        w2 = cvtpk_bf16(S1[r0 + 4], S1[r0 + 5]);                               \
        w3 = cvtpk_bf16(S1[r0 + 6], S1[r0 + 7]);                               \
      }                                                                        \
      asm("v_permlane32_swap_b32 %0, %1" : "+v"(w0), "+v"(w2));                \
      asm("v_permlane32_swap_b32 %0, %1" : "+v"(w1), "+v"(w3));                \
      u32x4 pw = {w0, w1, w2, w3};                                             \
      bf16x8 pf = __builtin_bit_cast(bf16x8, pw);                              \
      O0 = __builtin_amdgcn_mfma_f32_32x32x16_bf16(vf[kkt],     pf, O0, 0, 0, 0); \
      O1 = __builtin_amdgcn_mfma_f32_32x32x16_bf16(vf[4 + kkt], pf, O1, 0, 0, 0); \
    }                                                                          \
    __builtin_amdgcn_s_setprio(0);                                             \
  }

#define ATTN_EPI(O0, O1, L_R, ROWBASE)                                         \
  {                                                                            \
    const float inv = 1.0f / L_R;                                              \
    _Pragma("unroll")                                                          \
    for (int g = 0; g < 4; g++) {                                              \
      bf16x4 t4a, t4b;                                                         \
      _Pragma("unroll")                                                        \
      for (int j = 0; j < 4; j++) {                                            \
        t4a[j] = (__bf16)(O0[4 * g + j] * inv);                                \
        t4b[j] = (__bf16)(O1[4 * g + j] * inv);                                \
      }                                                                        \
      *(bf16x4*)&Tl[trow][g * 8 + hi * 4]      = t4a;                          \
      *(bf16x4*)&Tl[trow][32 + g * 8 + hi * 4] = t4b;                          \
    }                                                                          \
    asm volatile("s_waitcnt lgkmcnt(0)" ::: "memory");                         \
    __builtin_amdgcn_sched_barrier(0);                                         \
    _Pragma("unroll")                                                          \
    for (int i = 0; i < 4; i++) {                                              \
      bf16x8 z = *(const bf16x8*)&Tl[rr][ch + i * 8];                          \
      *(bf16x8*)&Z[((size_t)b * S + (ROWBASE) + rr) * 1024 + h * 64 +          \
                   ch + i * 8] = z;                                            \
    }                                                                          \
    asm volatile("s_waitcnt lgkmcnt(0)" ::: "memory");                         \
    __builtin_amdgcn_sched_barrier(0);                                         \
  }

__global__ __launch_bounds__(256, 2) void attn_fwd(
    const __bf16* __restrict__ QKV, const __bf16* __restrict__ VT,
    __bf16* __restrict__ Z) {
    const int S = 2048, LDQ = 3072;
    // Bijective XCD-chunk swizzle (512 blocks, 512%8==0; 2MB K/V per XCD).
    const int dd = blockIdx.x;
    const int blk = (dd & 7) * 64 + (dd >> 3);
    const int qt = blk & 7, bh = blk >> 3, b = bh >> 4, h = bh & 15;
    const int tid = threadIdx.x, wid = tid >> 6, lane = tid & 63;
    const int l31 = lane & 31, hi = lane >> 5;

    __shared__ __bf16 smem[16384];   // 32 KB (K/V dbuf; epilogue Tl overlays)

    const __bf16* Qb = QKV + (size_t)b * S * LDQ + h * 64;
    const __bf16* Kb = Qb + 1024;
    const __bf16* Vb = VT + (size_t)bh * 64 * S;
    const int qrowA = qt * 256 + wid * 32;
    const int qrowB = qrowA + 128;

    bf16x8 qfA[4], qfB[4];
#pragma unroll
    for (int kk = 0; kk < 4; kk++) {
        qfA[kk] = *(const bf16x8*)(Qb + (size_t)(qrowA + l31) * LDQ + kk * 16 + hi * 8);
        qfB[kk] = *(const bf16x8*)(Qb + (size_t)(qrowB + l31) * LDQ + kk * 16 + hi * 8);
    }

    const int f0 = wid * 2, f1 = wid * 2 + 1;
    const int kr0 = (f0 >> 2) * 32 + l31, kc0 = (f0 & 3) * 16 + hi * 8;
    const int kr1 = (f1 >> 2) * 32 + l31, kc1 = (f1 & 3) * 16 + hi * 8;
    const int vr0 = kr0, vs0 = kc0;
    const int vr1 = kr1, vs1 = kc1;
    const int ldst = lane * 16;

    f32x16 oA0 = fzero16(), oA1 = fzero16();
    f32x16 oB0 = fzero16(), oB1 = fzero16();
    float m_rA = -1e30f, l_rA = 0.f, m_rB = -1e30f, l_rB = 0.f;
    const float csc = 0.18033688011f;   // log2(e) / sqrt(64)

    gload_lds16(Kb + (size_t)kr0 * LDQ + kc0, (char*)smem + f0 * 1024 + ldst);
    gload_lds16(Kb + (size_t)kr1 * LDQ + kc1, (char*)smem + f1 * 1024 + ldst);
    gload_lds16(Vb + (size_t)vr0 * S + vs0,   (char*)smem + 16384 + f0 * 1024 + ldst);
    gload_lds16(Vb + (size_t)vr1 * S + vs1,   (char*)smem + 16384 + f1 * 1024 + ldst);
    asm volatile("s_waitcnt vmcnt(0)" ::: "memory");
    __syncthreads();

    int cur = 0;
    for (int t0 = 0; t0 < S; t0 += 64, cur ^= 1) {
        if (t0 + 64 < S) {
            char* kl = (char*)smem + (cur ^ 1) * 8192;
            char* vl = (char*)smem + 16384 + (cur ^ 1) * 8192;
            gload_lds16(Kb + (size_t)(t0 + 64 + kr0) * LDQ + kc0, kl + f0 * 1024 + ldst);
            gload_lds16(Kb + (size_t)(t0 + 64 + kr1) * LDQ + kc1, kl + f1 * 1024 + ldst);
            gload_lds16(Vb + (size_t)vr0 * S + t0 + 64 + vs0,     vl + f0 * 1024 + ldst);
            gload_lds16(Vb + (size_t)vr1 * S + t0 + 64 + vs1,     vl + f1 * 1024 + ldst);
        }
        const char* kbase = (const char*)smem + cur * 8192;
        const char* vbase = (const char*)smem + 16384 + cur * 8192;

        bf16x8 kf[8];
#pragma unroll
        for (int f = 0; f < 8; f++)
            kf[f] = *(const bf16x8*)(kbase + f * 1024 + ldst);
        f32x16 sA0 = fzero16(), sA1 = fzero16();
        f32x16 sB0 = fzero16(), sB1 = fzero16();
        __builtin_amdgcn_s_setprio(1);
#pragma unroll
        for (int kk = 0; kk < 4; kk++) {
            sA0 = __builtin_amdgcn_mfma_f32_32x32x16_bf16(kf[kk],     qfA[kk], sA0, 0, 0, 0);
            sA1 = __builtin_amdgcn_mfma_f32_32x32x16_bf16(kf[4 + kk], qfA[kk], sA1, 0, 0, 0);
        }
#pragma unroll
        for (int kk = 0; kk < 4; kk++) {
            sB0 = __builtin_amdgcn_mfma_f32_32x32x16_bf16(kf[kk],     qfB[kk], sB0, 0, 0, 0);
            sB1 = __builtin_amdgcn_mfma_f32_32x32x16_bf16(kf[4 + kk], qfB[kk], sB1, 0, 0, 0);
        }
        __builtin_amdgcn_s_setprio(0);

        bf16x8 vf[8];
#pragma unroll
        for (int f = 0; f < 8; f++)
            vf[f] = *(const bf16x8*)(vbase + f * 1024 + ldst);

        ATTN_SM_PV(sA0, sA1, m_rA, l_rA, oA0, oA1)
        ATTN_SM_PV(sB0, sB1, m_rB, l_rB, oB0, oB1)

        asm volatile("s_waitcnt vmcnt(0)" ::: "memory");
        __syncthreads();
    }

    __bf16 (*Tl)[72] = (__bf16 (*)[72])smem;
    const int trow = wid * 32 + l31;
    const int rr = wid * 32 + (lane >> 1);
    const int ch = (lane & 1) * 32;
    ATTN_EPI(oA0, oA1, l_rA, qt * 256)
    ATTN_EPI(oB0, oB1, l_rB, qt * 256 + 128)
}

// ---------------------------------------------------------------------------
// Launcher (4 kernels total)
// ---------------------------------------------------------------------------
extern "C" void kernel_launch(void* const* d_in, const int* in_sizes, int n_in,
                              void* d_out, int out_size, void* d_ws, size_t ws_size,
                              hipStream_t stream) {
    const float* x  = (const float*)d_in[0];
    const float* Wq = (const float*)d_in[1];
    const float* Wk = (const float*)d_in[2];
    const float* Wv = (const float*)d_in[3];
    const float* bq = (const float*)d_in[4];
    const float* bk = (const float*)d_in[5];
    const float* bv = (const float*)d_in[6];
    const float* Wo = (const float*)d_in[7];
    const float* bo = (const float*)d_in[8];
    float* out = (float*)d_out;

    // workspace carve-up (~109 MB)
    char* p = (char*)d_ws;
    __bf16* xb   = (__bf16*)p; p += 8192L * 1024 * 2;
    __bf16* Wqkv = (__bf16*)p; p += 3072L * 1024 * 2;
    float*  bqkv = (float*)p;  p += 3072L * 4;
    __bf16* QKV  = (__bf16*)p; p += 8192L * 3072 * 2;
    __bf16* VTb  = (__bf16*)p; p += 64L * 64 * 2048 * 2;
    __bf16* Zb   = (__bf16*)p; p += 8192L * 1024 * 2;
    __bf16* Wot  = (__bf16*)p; p += 1024L * 1024 * 2;

    // all preprocessing in one launch: 8192 cvt + 4096 packs + 12 bias blocks
    prep<<<12300, 256, 0, stream>>>(x, xb, Wq, Wk, Wv, Wo, Wqkv, Wot,
                                    bq, bk, bv, bqkv);

    // QKV projection: [8192,1024] x [1024,3072] + bias; Q,K -> QKV row-major,
    // V -> VT transposed. 256x128 tile, 512 threads.
    gemm_qkv<<<dim3(24, 32), 512, 0, stream>>>(xb, Wqkv, bqkv, QKV, VTb, 1024);
    attn_fwd<<<512, 256, 0, stream>>>(QKV, VTb, Zb);
    // out projection: [8192,1024] x [1024,1024] + bo -> f32 out
    gemm_bt<true><<<dim3(8, 32), 512, 0, stream>>>(Zb, Wot, bo, out,
                                                   8192, 1024, 1024, 1024);
}